// Round 1
// baseline (8774.787 us; speedup 1.0000x reference)
//
#include <hip/hip_runtime.h>

// LSTM LM forward on gfx950.
// R11 = quad-chain phase-staggered restructure of R10.
// Key insight: per-step time was ~6900 cyc = C(~1000 compute) + L(~5900
// fabric round trip for the agent-scope H exchange). The 4 batch groups are
// INDEPENDENT recurrences, so each wave now serves all 4 groups in staggered
// phases: compute g0(s) -> publish -> g1(s) -> ... -> g3(s) -> poll g0(s+1).
// A group's publish gets 3 full compute phases to propagate before its
// consumers re-poll => per-chain-step D = max(C, (C+L)/4) instead of C+L.
//  - 32 WGs x 256 thr (was 128): wave (wg,wv) owns h-slot q=wg*4+wv for ALL
//    4 groups; wfrag[20] weights shared across groups (same q => 0 extra VGPR).
//  - Per-CU per-phase work identical to R10's per-step work (C unchanged).
//  - Per-phase barrier => Hs single-buffered per group (read(s) and
//    stage(s+1) separated by 3 intervening barriers); Xs LDS dropped: x
//    B-fragments register-prefetched one phase ahead from immutable xbf.
//  - Exchange protocol unchanged: tagged u64 {step, 2xbf16}, relaxed
//    AGENT-scope atomics, 16-word pipelined poll + reload-all resweep,
//    x-part MFMAs overlap the poll wait.
// Carried from R10: deferred Y flush via yred parity LDS + reduce_y kernel,
// 2-way split accumulator, folded head Y = H.v + c0.

typedef short bf16x8 __attribute__((ext_vector_type(8)));
typedef float f32x4  __attribute__((ext_vector_type(4)));
typedef unsigned short ushort_t;
typedef unsigned long long u64;

#define S_LEN 1024
#define NB    64
#define NH    512
#define NE    128
#define NGRP  4
#define NWPG  32              // h-slot WGs (ypart stride; = grid size now)
#define NWGT  32              // total WGs (quad-chain: each serves 4 groups)

// workspace byte offsets (unchanged from R10)
#define OFF_WPACK 0UL                          // 128*20*64*16 = 2,621,440
#define OFF_XBF   2621440UL                    // 1024*64*128*2 = 16,777,216
#define OFF_EXCH  19398656UL                   // 4 grp * 2 par * 4096 u64 * 8 = 262,144
#define OFF_V     19660800UL                   // 512*4
#define OFF_C0S   19662848UL                   // 16
#define OFF_YPART 19663360UL                   // 1024*4*32*16*4 = 8,388,608

__device__ __forceinline__ ushort_t f2bf(float f){
    union { float f; unsigned u; } v; v.f = f;
    unsigned u = v.u;
    unsigned r = (u + 0x7fffu + ((u >> 16) & 1u)) >> 16;
    return (ushort_t)r;
}
__device__ __forceinline__ float sigm(float x){ return 1.f / (1.f + __expf(-x)); }
__device__ __forceinline__ float tanh_(float x){ float e = __expf(2.f * x); return (e - 1.f) / (e + 1.f); }

// ---- prep: pack W into MFMA A-operand fragments (bf16) ----------------------
// wpack[q][ks][lane][j]: A[m=lane&15][k=32*ks+(lane>>4)*8+j]; m -> h=4q+(m>>2),
// gate g=m&3; k<512: W_h[g][k][h]; k>=512: W_x[g][k-512][h]
__global__ void pack_weights(const float* __restrict__ Wxi, const float* __restrict__ Whi,
                             const float* __restrict__ Wxf, const float* __restrict__ Whf,
                             const float* __restrict__ Wxo, const float* __restrict__ Who,
                             const float* __restrict__ Wxc, const float* __restrict__ Whc,
                             ushort_t* __restrict__ wpack){
    int bid = blockIdx.x;            // = q*20 + ks
    int q = bid / 20, ks = bid % 20;
    int l = threadIdx.x;             // 0..63
    int m = l & 15, quad = l >> 4;
    int h = q * 4 + (m >> 2), g = m & 3;
    const float* Wh = (g == 0) ? Whi : (g == 1) ? Whf : (g == 2) ? Who : Whc;
    const float* Wx = (g == 0) ? Wxi : (g == 1) ? Wxf : (g == 2) ? Wxo : Wxc;
    union { ushort_t u[8]; uint4 v4; } tmp;
    #pragma unroll
    for (int j = 0; j < 8; j++){
        int k = ks * 32 + quad * 8 + j;
        float w = (k < NH) ? Wh[(size_t)k * NH + h] : Wx[(size_t)(k - NH) * NH + h];
        tmp.u[j] = f2bf(w);
    }
    *(uint4*)(wpack + ((size_t)bid * 64 + l) * 8) = tmp.v4;
}

// ---- prep: bf16 embeddings, layout [s][b][e] --------------------------------
__global__ void prep_x(const int* __restrict__ inputs, const float* __restrict__ emb,
                       ushort_t* __restrict__ xbf){
    unsigned tid = blockIdx.x * 256u + threadIdx.x;   // = (s*64+b)*128 + e
    unsigned e = tid & 127u;
    unsigned b = (tid >> 7) & 63u;
    unsigned s = tid >> 13;
    int row = inputs[(size_t)b * S_LEN + s];
    xbf[tid] = f2bf(emb[(size_t)row * NE + e]);
}

// ---- prep: v = W_hq @ dense_w, c0, exch init (H0, tag 0, parity 0) ----------
__global__ void prep_v(const float* __restrict__ Whq, const float* __restrict__ bq,
                       const float* __restrict__ dw, const float* __restrict__ db,
                       const float* __restrict__ H0, float* __restrict__ v,
                       float* __restrict__ c0, u64* __restrict__ exch){
    int t = threadIdx.x;   // 512 threads, 1 block
    float a = 0.f;
    for (int e = 0; e < NE; e++) a += Whq[(size_t)t * NE + e] * dw[e];
    v[t] = a;
    if (t == 0){
        float c = db[0];
        for (int e = 0; e < NE; e++) c += bq[e] * dw[e];
        *c0 = c;
    }
    // exch layout: [grp][parity][16 b_local][256 hpair] of u64 {tag, data}
    int p = t & 255, half = t >> 8;
    for (int b = half * 32; b < half * 32 + 32; b++){
        unsigned lo = (unsigned)f2bf(H0[(size_t)b * NH + 2 * p]) |
                      ((unsigned)f2bf(H0[(size_t)b * NH + 2 * p + 1]) << 16);
        exch[(size_t)(b >> 4) * 8192 + (size_t)(b & 15) * 256 + p] = (u64)lo;  // tag=0
    }
}

// ---- final: Y[s,b] = c0 + sum_wgin ypart[s][grp(b)][wgin][b&15] -------------
__global__ void reduce_y(const float* __restrict__ ypart, const float* __restrict__ c0,
                         float* __restrict__ dout){
    int t = blockIdx.x * 256 + threadIdx.x;   // t = s*64 + b, 65536 total
    int s = t >> 6, b = t & 63;
    int g = b >> 4, bl = b & 15;
    float a = *c0;
    const float* base = ypart + (((size_t)s * NGRP + g) * NWPG) * 16 + bl;
    #pragma unroll 4
    for (int w = 0; w < NWPG; w++) a += base[w * 16];
    dout[t] = a;
}

// ---- the recurrence: quad-chain phase-staggered -----------------------------
__launch_bounds__(256, 1)
__global__ void lstm_coop(const float* __restrict__ C0,
                          const float* __restrict__ b_i, const float* __restrict__ b_f,
                          const float* __restrict__ b_o, const float* __restrict__ b_c,
                          const ushort_t* __restrict__ wpack, const ushort_t* __restrict__ xbf,
                          u64* __restrict__ exch, const float* __restrict__ v,
                          float* __restrict__ ypart, float* __restrict__ dout){
    // LDS: Hs single-buffered per group [4][16 rows][65 uint4] (+pad -> dword
    // stride 260, conflict-free staging). Safe without parity: read of
    // Hs[g](s) happens before this wave's NEXT phase barrier; stage of
    // Hs[g](s+1) happens after 3 more barriers. yred: [group][parity] wave
    // partials for the deferred Y flush.
    __shared__ uint4 Hs[NGRP][16][65];
    __shared__ float yred[NGRP][2][4][16];

    const int tid  = threadIdx.x;
    const int lane = tid & 63;
    const int wv   = tid >> 6;
    const int wg   = blockIdx.x;           // 0..31
    const int q    = wg * 4 + wv;          // h-slot 0..127 (all 4 groups)
    const int quad = lane >> 4;
    const int col  = lane & 15;
    const int h    = q * 4 + quad;         // this lane's h column

    // persistent weights: 20 A-fragments (K=640), shared across all 4 groups
    bf16x8 wfrag[20];
    #pragma unroll
    for (int ks = 0; ks < 20; ks++)
        wfrag[ks] = *(const bf16x8*)(wpack + ((size_t)(q * 20 + ks) * 64 + lane) * 8);

    const float bias0 = b_i[h], bias1 = b_f[h], bias2 = b_o[h], bias3 = b_c[h];
    const float vv = v[h];
    float Cc[NGRP];
    #pragma unroll
    for (int g = 0; g < NGRP; g++)
        Cc[g] = C0[(size_t)(g * 16 + col) * NH + h];

    unsigned* HsD = (unsigned*)Hs;
    const char* HsB = (const char*)Hs;

    // x B-fragment prologue load for phase (g=0, s=0): lane needs
    // x[e = kx*32 + quad*8 + j][b = g*16+col] -> 16B contiguous in xbf[s][b][e]
    bf16x8 xc0, xc1, xc2, xc3;
    {
        const ushort_t* xb = xbf + (size_t)col * NE + quad * 8;
        xc0 = *(const bf16x8*)(xb);
        xc1 = *(const bf16x8*)(xb + 32);
        xc2 = *(const bf16x8*)(xb + 64);
        xc3 = *(const bf16x8*)(xb + 96);
    }

    for (int s = 0; s < S_LEN; s++){
        const unsigned tag = (unsigned)s;
        #pragma unroll
        for (int g = 0; g < NGRP; g++){
            // ---- issue poll loads for H_g(s) --------------------------------
            const u64* ex = exch + (size_t)g * 8192 + (size_t)(s & 1) * 4096;
            u64 hv[16];
            #pragma unroll
            for (int j = 0; j < 16; j++)
                hv[j] = __hip_atomic_load(ex + (size_t)j * 256 + tid, __ATOMIC_RELAXED,
                                          __HIP_MEMORY_SCOPE_AGENT);

            // ---- x prefetch for the NEXT phase (lands during poll/compute) --
            const int gn = (g + 1) & 3;
            const int sn = (g == 3) ? ((s + 1 < S_LEN) ? s + 1 : s) : s;
            const ushort_t* xb = xbf + ((size_t)sn * NB + gn * 16 + col) * NE + quad * 8;
            bf16x8 xn0 = *(const bf16x8*)(xb);
            bf16x8 xn1 = *(const bf16x8*)(xb + 32);
            bf16x8 xn2 = *(const bf16x8*)(xb + 64);
            bf16x8 xn3 = *(const bf16x8*)(xb + 96);

            // ---- x-part MFMAs overlap the poll (xc* loaded last phase) ------
            f32x4 acc0 = (f32x4){0.f, 0.f, 0.f, 0.f};
            f32x4 acc1 = (f32x4){0.f, 0.f, 0.f, 0.f};
            acc0 = __builtin_amdgcn_mfma_f32_16x16x32_bf16(wfrag[16], xc0, acc0, 0, 0, 0);
            acc1 = __builtin_amdgcn_mfma_f32_16x16x32_bf16(wfrag[17], xc1, acc1, 0, 0, 0);
            acc0 = __builtin_amdgcn_mfma_f32_16x16x32_bf16(wfrag[18], xc2, acc0, 0, 0, 0);
            acc1 = __builtin_amdgcn_mfma_f32_16x16x32_bf16(wfrag[19], xc3, acc1, 0, 0, 0);

            // ---- finish poll: reload-all resweep until every tag matches ----
            for (;;){
                unsigned bad = 0;
                #pragma unroll
                for (int j = 0; j < 16; j++)
                    bad |= ((unsigned)(hv[j] >> 32) != tag) ? 1u : 0u;
                if (!bad) break;
                __builtin_amdgcn_s_sleep(1);
                #pragma unroll
                for (int j = 0; j < 16; j++)
                    hv[j] = __hip_atomic_load(ex + (size_t)j * 256 + tid, __ATOMIC_RELAXED,
                                              __HIP_MEMORY_SCOPE_AGENT);
            }
            #pragma unroll
            for (int j = 0; j < 16; j++)
                HsD[g * 4160 + j * 260 + tid] = (unsigned)hv[j];  // Hs[g], row j
            __syncthreads();   // one barrier per phase: Hs[g](s) ready

            // ---- flush previous step's Y partials for this group ------------
            if (tid < 16 && s > 0)
                ypart[(((size_t)(s - 1) * NGRP + g) * NWPG + wg) * 16 + tid] =
                    yred[g][(s - 1) & 1][0][tid] + yred[g][(s - 1) & 1][1][tid] +
                    yred[g][(s - 1) & 1][2][tid] + yred[g][(s - 1) & 1][3][tid];

            // ---- H-part: 16 MFMA from LDS (2-way split accumulator) ---------
            #pragma unroll
            for (int ks = 0; ks < 16; ks++){
                bf16x8 bfr = *(const bf16x8*)(HsB + g * 16640 + col * 1040 + ks * 64 + quad * 16);
                if (ks & 1) acc1 = __builtin_amdgcn_mfma_f32_16x16x32_bf16(wfrag[ks], bfr, acc1, 0, 0, 0);
                else        acc0 = __builtin_amdgcn_mfma_f32_16x16x32_bf16(wfrag[ks], bfr, acc0, 0, 0, 0);
            }
            f32x4 acc = acc0 + acc1;

            // ---- cell update: acc regs = {i,f,o,c} for (b, h) ---------------
            float I = sigm(acc[0] + bias0);
            float F = sigm(acc[1] + bias1);
            float O = sigm(acc[2] + bias2);
            float G = tanh_(acc[3] + bias3);
            float Cn = F * Cc[g] + I * G;
            float Hn = O * tanh_(Cn);
            Cc[g] = Cn;

            // ---- publish H_g(s+1): tagged u64, lane-pair packed -------------
            float Hn_hi = __shfl_xor(Hn, 16, 64);         // partner quad's value
            {
                unsigned lo = (unsigned)f2bf(Hn) | ((unsigned)f2bf(Hn_hi) << 16);
                if ((quad & 1) == 0 && s < S_LEN - 1){
                    u64* ew = exch + (size_t)g * 8192 + (size_t)((s + 1) & 1) * 4096;
                    unsigned idx = (unsigned)col * 256 + (unsigned)(q * 2) + (unsigned)(quad >> 1);
                    u64 word = ((u64)(unsigned)(s + 1) << 32) | (u64)lo;
                    __hip_atomic_store(ew + idx, word, __ATOMIC_RELAXED,
                                       __HIP_MEMORY_SCOPE_AGENT);
                }
            }

            // ---- Y partial into LDS (read after phase-g barrier of s+1) -----
            float p = Hn * vv;
            p += __shfl_xor(p, 16, 64);
            p += __shfl_xor(p, 32, 64);
            if (quad == 0) yred[g][s & 1][wv][col] = p;

            if (s == S_LEN - 1){
                int b = g * 16 + col;
                dout[65536 + (size_t)b * NH + h] = Hn;   // final H
                dout[98304 + (size_t)b * NH + h] = Cn;   // final C
            }

            // ---- rotate x fragments -----------------------------------------
            xc0 = xn0; xc1 = xn1; xc2 = xn2; xc3 = xn3;
        }
    }
    // final Y flush for s = S_LEN-1, all groups
    __syncthreads();
    if (tid < 64){
        int gg = tid >> 4, t = tid & 15;
        ypart[(((size_t)(S_LEN - 1) * NGRP + gg) * NWPG + wg) * 16 + t] =
            yred[gg][(S_LEN - 1) & 1][0][t] + yred[gg][(S_LEN - 1) & 1][1][t] +
            yred[gg][(S_LEN - 1) & 1][2][t] + yred[gg][(S_LEN - 1) & 1][3][t];
    }
}

extern "C" void kernel_launch(void* const* d_in, const int* in_sizes, int n_in,
                              void* d_out, int out_size, void* d_ws, size_t ws_size,
                              hipStream_t stream){
    const int*   inputs = (const int*)  d_in[0];
    const float* H0     = (const float*)d_in[1];
    const float* C0     = (const float*)d_in[2];
    const float* emb    = (const float*)d_in[3];
    const float* W_xi   = (const float*)d_in[4];
    const float* W_hi   = (const float*)d_in[5];
    const float* b_i    = (const float*)d_in[6];
    const float* W_xf   = (const float*)d_in[7];
    const float* W_hf   = (const float*)d_in[8];
    const float* b_f    = (const float*)d_in[9];
    const float* W_xo   = (const float*)d_in[10];
    const float* W_ho   = (const float*)d_in[11];
    const float* b_o    = (const float*)d_in[12];
    const float* W_xc   = (const float*)d_in[13];
    const float* W_hc   = (const float*)d_in[14];
    const float* b_c    = (const float*)d_in[15];
    const float* W_hq   = (const float*)d_in[16];
    const float* b_q    = (const float*)d_in[17];
    const float* dw     = (const float*)d_in[18];
    const float* db     = (const float*)d_in[19];
    float* dout = (float*)d_out;

    char* ws = (char*)d_ws;
    ushort_t* wpack = (ushort_t*)(ws + OFF_WPACK);
    ushort_t* xbf   = (ushort_t*)(ws + OFF_XBF);
    u64*      exch  = (u64*)     (ws + OFF_EXCH);
    float*    v     = (float*)   (ws + OFF_V);
    float*    c0    = (float*)   (ws + OFF_C0S);
    float*    ypart = (float*)   (ws + OFF_YPART);

    pack_weights<<<dim3(128 * 20), dim3(64), 0, stream>>>(W_xi, W_hi, W_xf, W_hf,
                                                          W_xo, W_ho, W_xc, W_hc, wpack);
    prep_x<<<dim3((S_LEN * NB * NE) / 256), dim3(256), 0, stream>>>(inputs, emb, xbf);
    prep_v<<<dim3(1), dim3(512), 0, stream>>>(W_hq, b_q, dw, db, H0, v, c0, exch);

    void* args[] = { (void*)&C0, (void*)&b_i, (void*)&b_f, (void*)&b_o, (void*)&b_c,
                     (void*)&wpack, (void*)&xbf, (void*)&exch, (void*)&v,
                     (void*)&ypart, (void*)&dout };
    hipLaunchCooperativeKernel((void*)lstm_coop, dim3(NWGT), dim3(256), args, 0, stream);

    reduce_y<<<dim3(65536 / 256), dim3(256), 0, stream>>>(ypart, c0, dout);
}

// Round 2
// 7689.488 us; speedup vs baseline: 1.1411x; 1.1411x over previous
//
#include <hip/hip_runtime.h>

// LSTM LM forward on gfx950.
// R12 = R10 structure (128 WGs, 4 groups x 32 WGs x 16 batches, 1 h-slot/wave,
// wfrag[20], proven 2941us) + counter-based ready signal for the H exchange.
// R11's quad-chain stagger was an algebra error (4 phases/step => step still
// C+L, plus 4x barrier/poll overhead; measured 8.6ms). Reverted.
// R10's wait was ~5 reload-all resweep rounds/step (FETCH 677KB/step vs 128KB
// data => ~5x re-read; 4MB/step of coherent poll loads hammering the same
// exchange lines). R12 splits ready-detection from data-read:
//  - Publisher: tagged data stores (unchanged) -> wave-wide s_waitcnt
//    vmcnt(0) (stores ack'd at coherence point) -> lane0 fetch_add(+1) to
//    per-group counter. 128 publisher waves/group/step.
//  - Consumer: poll the single counter word (1 broadcast load/wave/round,
//    overlapped with x-part MFMAs) until cnt >= 128*s, then ONE data sweep.
//  - Tags kept + verified; reload-all resweep remains as correctness
//    fallback if the counter ever leads the data. Protocol safe regardless
//    of fence strength.
// Carried from R10: tagged u64 {step, 2xbf16} H exchange via relaxed
// AGENT-scope atomics, Hs parity dbuf + Xs triple-buf, one barrier/step,
// deferred Y flush via yred parity LDS + reduce_y, 2-way split accumulator,
// folded head Y = H.v + c0.

typedef short bf16x8 __attribute__((ext_vector_type(8)));
typedef float f32x4  __attribute__((ext_vector_type(4)));
typedef unsigned short ushort_t;
typedef unsigned long long u64;

#define S_LEN 1024
#define NB    64
#define NH    512
#define NE    128
#define NGRP  4
#define NWPG  32              // WGs per group
#define NWGT  128             // total WGs

// workspace byte offsets
#define OFF_WPACK 0UL                          // 128*20*64*16 = 2,621,440
#define OFF_XBF   2621440UL                    // 1024*64*128*2 = 16,777,216
#define OFF_EXCH  19398656UL                   // 4 grp * 2 par * 4096 u64 * 8 = 262,144
#define OFF_V     19660800UL                   // 512*4
#define OFF_C0S   19662848UL                   // 16
#define OFF_CNT   19663104UL                   // 4 u64 counters, 64B stride = 256
#define OFF_YPART 19663360UL                   // 1024*4*32*16*4 = 8,388,608

__device__ __forceinline__ ushort_t f2bf(float f){
    union { float f; unsigned u; } v; v.f = f;
    unsigned u = v.u;
    unsigned r = (u + 0x7fffu + ((u >> 16) & 1u)) >> 16;
    return (ushort_t)r;
}
__device__ __forceinline__ float sigm(float x){ return 1.f / (1.f + __expf(-x)); }
__device__ __forceinline__ float tanh_(float x){ float e = __expf(2.f * x); return (e - 1.f) / (e + 1.f); }

// ---- prep: pack W into MFMA A-operand fragments (bf16) ----------------------
// wpack[q][ks][lane][j]: A[m=lane&15][k=32*ks+(lane>>4)*8+j]; m -> h=4q+(m>>2),
// gate g=m&3; k<512: W_h[g][k][h]; k>=512: W_x[g][k-512][h]
__global__ void pack_weights(const float* __restrict__ Wxi, const float* __restrict__ Whi,
                             const float* __restrict__ Wxf, const float* __restrict__ Whf,
                             const float* __restrict__ Wxo, const float* __restrict__ Who,
                             const float* __restrict__ Wxc, const float* __restrict__ Whc,
                             ushort_t* __restrict__ wpack){
    int bid = blockIdx.x;            // = q*20 + ks
    int q = bid / 20, ks = bid % 20;
    int l = threadIdx.x;             // 0..63
    int m = l & 15, quad = l >> 4;
    int h = q * 4 + (m >> 2), g = m & 3;
    const float* Wh = (g == 0) ? Whi : (g == 1) ? Whf : (g == 2) ? Who : Whc;
    const float* Wx = (g == 0) ? Wxi : (g == 1) ? Wxf : (g == 2) ? Wxo : Wxc;
    union { ushort_t u[8]; uint4 v4; } tmp;
    #pragma unroll
    for (int j = 0; j < 8; j++){
        int k = ks * 32 + quad * 8 + j;
        float w = (k < NH) ? Wh[(size_t)k * NH + h] : Wx[(size_t)(k - NH) * NH + h];
        tmp.u[j] = f2bf(w);
    }
    *(uint4*)(wpack + ((size_t)bid * 64 + l) * 8) = tmp.v4;
}

// ---- prep: bf16 embeddings, layout [s][b][e] --------------------------------
__global__ void prep_x(const int* __restrict__ inputs, const float* __restrict__ emb,
                       ushort_t* __restrict__ xbf){
    unsigned tid = blockIdx.x * 256u + threadIdx.x;   // = (s*64+b)*128 + e
    unsigned e = tid & 127u;
    unsigned b = (tid >> 7) & 63u;
    unsigned s = tid >> 13;
    int row = inputs[(size_t)b * S_LEN + s];
    xbf[tid] = f2bf(emb[(size_t)row * NE + e]);
}

// ---- prep: v = W_hq @ dense_w, c0, exch init (H0, tag 0), counters = 0 ------
__global__ void prep_v(const float* __restrict__ Whq, const float* __restrict__ bq,
                       const float* __restrict__ dw, const float* __restrict__ db,
                       const float* __restrict__ H0, float* __restrict__ v,
                       float* __restrict__ c0, u64* __restrict__ exch,
                       u64* __restrict__ cnt){
    int t = threadIdx.x;   // 512 threads, 1 block
    float a = 0.f;
    for (int e = 0; e < NE; e++) a += Whq[(size_t)t * NE + e] * dw[e];
    v[t] = a;
    if (t == 0){
        float c = db[0];
        for (int e = 0; e < NE; e++) c += bq[e] * dw[e];
        *c0 = c;
    }
    if (t < 4) cnt[(size_t)t * 8] = 0;   // per-group ready counters
    // exch layout: [grp][parity][16 b_local][256 hpair] of u64 {tag, data}
    int p = t & 255, half = t >> 8;
    for (int b = half * 32; b < half * 32 + 32; b++){
        unsigned lo = (unsigned)f2bf(H0[(size_t)b * NH + 2 * p]) |
                      ((unsigned)f2bf(H0[(size_t)b * NH + 2 * p + 1]) << 16);
        exch[(size_t)(b >> 4) * 8192 + (size_t)(b & 15) * 256 + p] = (u64)lo;  // tag=0
    }
}

// ---- final: Y[s,b] = c0 + sum_wgin ypart[s][grp(b)][wgin][b&15] -------------
__global__ void reduce_y(const float* __restrict__ ypart, const float* __restrict__ c0,
                         float* __restrict__ dout){
    int t = blockIdx.x * 256 + threadIdx.x;   // t = s*64 + b, 65536 total
    int s = t >> 6, b = t & 63;
    int g = b >> 4, bl = b & 15;
    float a = *c0;
    const float* base = ypart + (((size_t)s * NGRP + g) * NWPG) * 16 + bl;
    #pragma unroll 4
    for (int w = 0; w < NWPG; w++) a += base[w * 16];
    dout[t] = a;
}

// ---- the recurrence ---------------------------------------------------------
__launch_bounds__(256, 1)
__global__ void lstm_coop(const float* __restrict__ C0,
                          const float* __restrict__ b_i, const float* __restrict__ b_f,
                          const float* __restrict__ b_o, const float* __restrict__ b_c,
                          const ushort_t* __restrict__ wpack, const ushort_t* __restrict__ xbf,
                          u64* __restrict__ exch, u64* __restrict__ cnt,
                          const float* __restrict__ v,
                          float* __restrict__ ypart, float* __restrict__ dout){
    // LDS: Hs double-buffered [2][16 rows][65 uint4] (+pad -> dword stride 260,
    // conflict-free staging), Xs triple-buffered [3][16][17] uint4,
    // yred parity-double-buffered wave partials.
    __shared__ uint4 Hs[2][16][65];
    __shared__ uint4 Xs[3][16][17];
    __shared__ float yred[2][4][16];

    const int tid  = threadIdx.x;
    const int lane = tid & 63;
    const int wv   = tid >> 6;
    const int wg   = blockIdx.x;
    const int g    = wg >> 5;              // batch group 0..3
    const int wgin = wg & 31;              // WG index within group
    const int q    = wgin * 4 + wv;        // h-slot 0..127
    const int quad = lane >> 4;
    const int col  = lane & 15;
    const int h    = q * 4 + quad;         // this lane's h column
    const int b    = g * 16 + col;         // this lane's batch

    // persistent weights: 20 A-fragments (K=640)
    bf16x8 wfrag[20];
    #pragma unroll
    for (int ks = 0; ks < 20; ks++)
        wfrag[ks] = *(const bf16x8*)(wpack + ((size_t)(q * 20 + ks) * 64 + lane) * 8);

    const float bias0 = b_i[h], bias1 = b_f[h], bias2 = b_o[h], bias3 = b_c[h];
    const float vv = v[h];
    float C = C0[(size_t)b * NH + h];

    u64* exg  = exch + (size_t)g * 8192;    // this group's double buffer
    u64* cntg = cnt + (size_t)g * 8;        // this group's ready counter (64B stride)

    const char* HsB = (const char*)Hs;
    const char* XsB = (const char*)Xs;
    unsigned* HsD = (unsigned*)Hs;

    // preload x tile for s=0 into Xs[0]; barrier so early x-MFMAs at s=0 are safe
    {
        const uint4* x0 = (const uint4*)(xbf + (size_t)(g * 16) * NE);
        Xs[0][tid >> 4][tid & 15] = x0[tid];
    }
    __syncthreads();

    for (int s = 0; s < S_LEN; s++){
        // x prefetch for s+1 (lands during poll)
        int sn = (s + 1 < S_LEN) ? s + 1 : s;
        uint4 xr = ((const uint4*)(xbf + ((size_t)sn * NB + g * 16) * NE))[tid];

        const u64* ex = exg + (size_t)(s & 1) * 4096;
        const unsigned tag = (unsigned)s;
        const u64 need = (u64)128 * (u64)s;   // 128 publisher waves/group/step

        // ---- issue first counter poll (overlaps x-part MFMAs) ----------------
        u64 cv = __hip_atomic_load(cntg, __ATOMIC_RELAXED, __HIP_MEMORY_SCOPE_AGENT);

        // ---- x-part MFMAs overlap the poll (Xs[s%3] synced at step s-1) ------
        f32x4 acc0 = (f32x4){0.f, 0.f, 0.f, 0.f};
        f32x4 acc1 = (f32x4){0.f, 0.f, 0.f, 0.f};
        #pragma unroll
        for (int kx = 0; kx < 4; kx++){
            bf16x8 bfr = *(const bf16x8*)(XsB + (s % 3) * 4352 + col * 272 + kx * 64 + quad * 16);
            if (kx & 1) acc1 = __builtin_amdgcn_mfma_f32_16x16x32_bf16(wfrag[16 + kx], bfr, acc1, 0, 0, 0);
            else        acc0 = __builtin_amdgcn_mfma_f32_16x16x32_bf16(wfrag[16 + kx], bfr, acc0, 0, 0, 0);
        }

        // ---- cheap wait: single-word counter poll ----------------------------
        while (cv < need){
            __builtin_amdgcn_s_sleep(1);
            cv = __hip_atomic_load(cntg, __ATOMIC_RELAXED, __HIP_MEMORY_SCOPE_AGENT);
        }

        // ---- one data sweep; tags verified (resweep = correctness fallback) --
        u64 hv[16];
        #pragma unroll
        for (int j = 0; j < 16; j++)
            hv[j] = __hip_atomic_load(ex + (size_t)j * 256 + tid, __ATOMIC_RELAXED,
                                      __HIP_MEMORY_SCOPE_AGENT);
        for (;;){
            unsigned bad = 0;
            #pragma unroll
            for (int j = 0; j < 16; j++)
                bad |= ((unsigned)(hv[j] >> 32) != tag) ? 1u : 0u;
            if (!bad) break;
            __builtin_amdgcn_s_sleep(1);
            #pragma unroll
            for (int j = 0; j < 16; j++)
                hv[j] = __hip_atomic_load(ex + (size_t)j * 256 + tid, __ATOMIC_RELAXED,
                                          __HIP_MEMORY_SCOPE_AGENT);
        }
        #pragma unroll
        for (int j = 0; j < 16; j++)
            HsD[(s & 1) * 4160 + j * 260 + tid] = (unsigned)hv[j];  // row j, dword tid
        Xs[(s + 1) % 3][tid >> 4][tid & 15] = xr;
        __syncthreads();   // the only in-loop barrier: Hs[s&1] + Xs ready

        // ---- flush previous step's Y partials (reuses this barrier) ----------
        if (tid < 16 && s > 0)
            ypart[(((size_t)(s - 1) * NGRP + g) * NWPG + wgin) * 16 + tid] =
                yred[(s - 1) & 1][0][tid] + yred[(s - 1) & 1][1][tid] +
                yred[(s - 1) & 1][2][tid] + yred[(s - 1) & 1][3][tid];

        // ---- H-part: 16 MFMA from LDS (2-way split accumulator) --------------
        #pragma unroll
        for (int ks = 0; ks < 16; ks++){
            bf16x8 bfr = *(const bf16x8*)(HsB + (s & 1) * 16640 + col * 1040 + ks * 64 + quad * 16);
            if (ks & 1) acc1 = __builtin_amdgcn_mfma_f32_16x16x32_bf16(wfrag[ks], bfr, acc1, 0, 0, 0);
            else        acc0 = __builtin_amdgcn_mfma_f32_16x16x32_bf16(wfrag[ks], bfr, acc0, 0, 0, 0);
        }
        f32x4 acc = acc0 + acc1;

        // ---- cell update: acc regs = {i,f,o,c} for (b, h) ---------------------
        float I = sigm(acc[0] + bias0);
        float F = sigm(acc[1] + bias1);
        float O = sigm(acc[2] + bias2);
        float G = tanh_(acc[3] + bias3);
        float Cn = F * C + I * G;
        float Hn = O * tanh_(Cn);
        C = Cn;

        // ---- publish H(s+1): tagged u64, lane-pair packed ---------------------
        float Hn_hi = __shfl_xor(Hn, 16, 64);         // partner quad's value
        {
            unsigned lo = (unsigned)f2bf(Hn) | ((unsigned)f2bf(Hn_hi) << 16);
            if ((quad & 1) == 0 && s < S_LEN - 1){
                u64* ew = exg + (size_t)((s + 1) & 1) * 4096;
                unsigned idx = (unsigned)col * 256 + (unsigned)(q * 2) + (unsigned)(quad >> 1);
                u64 word = ((u64)(unsigned)(s + 1) << 32) | (u64)lo;
                __hip_atomic_store(ew + idx, word, __ATOMIC_RELAXED,
                                   __HIP_MEMORY_SCOPE_AGENT);
            }
        }

        // ---- ready signal: stores ack'd (wave-wide vmcnt), then +1 -----------
        if (s < S_LEN - 1){
            asm volatile("s_waitcnt vmcnt(0)" ::: "memory");
            if (lane == 0)
                (void)__hip_atomic_fetch_add(cntg, 1ull, __ATOMIC_RELAXED,
                                             __HIP_MEMORY_SCOPE_AGENT);
        }

        // ---- Y partial into LDS (read after NEXT step's barrier) -------------
        float p = Hn * vv;
        p += __shfl_xor(p, 16, 64);
        p += __shfl_xor(p, 32, 64);
        if (quad == 0) yred[s & 1][wv][col] = p;

        if (s == S_LEN - 1){
            dout[65536 + (size_t)b * NH + h] = Hn;   // final H
            dout[98304 + (size_t)b * NH + h] = Cn;   // final C
        }
    }
    // final Y flush for s = S_LEN-1
    __syncthreads();
    if (tid < 16)
        ypart[(((size_t)(S_LEN - 1) * NGRP + g) * NWPG + wgin) * 16 + tid] =
            yred[(S_LEN - 1) & 1][0][tid] + yred[(S_LEN - 1) & 1][1][tid] +
            yred[(S_LEN - 1) & 1][2][tid] + yred[(S_LEN - 1) & 1][3][tid];
}

extern "C" void kernel_launch(void* const* d_in, const int* in_sizes, int n_in,
                              void* d_out, int out_size, void* d_ws, size_t ws_size,
                              hipStream_t stream){
    const int*   inputs = (const int*)  d_in[0];
    const float* H0     = (const float*)d_in[1];
    const float* C0     = (const float*)d_in[2];
    const float* emb    = (const float*)d_in[3];
    const float* W_xi   = (const float*)d_in[4];
    const float* W_hi   = (const float*)d_in[5];
    const float* b_i    = (const float*)d_in[6];
    const float* W_xf   = (const float*)d_in[7];
    const float* W_hf   = (const float*)d_in[8];
    const float* b_f    = (const float*)d_in[9];
    const float* W_xo   = (const float*)d_in[10];
    const float* W_ho   = (const float*)d_in[11];
    const float* b_o    = (const float*)d_in[12];
    const float* W_xc   = (const float*)d_in[13];
    const float* W_hc   = (const float*)d_in[14];
    const float* b_c    = (const float*)d_in[15];
    const float* W_hq   = (const float*)d_in[16];
    const float* b_q    = (const float*)d_in[17];
    const float* dw     = (const float*)d_in[18];
    const float* db     = (const float*)d_in[19];
    float* dout = (float*)d_out;

    char* ws = (char*)d_ws;
    ushort_t* wpack = (ushort_t*)(ws + OFF_WPACK);
    ushort_t* xbf   = (ushort_t*)(ws + OFF_XBF);
    u64*      exch  = (u64*)     (ws + OFF_EXCH);
    float*    v     = (float*)   (ws + OFF_V);
    float*    c0    = (float*)   (ws + OFF_C0S);
    u64*      cnt   = (u64*)     (ws + OFF_CNT);
    float*    ypart = (float*)   (ws + OFF_YPART);

    pack_weights<<<dim3(128 * 20), dim3(64), 0, stream>>>(W_xi, W_hi, W_xf, W_hf,
                                                          W_xo, W_ho, W_xc, W_hc, wpack);
    prep_x<<<dim3((S_LEN * NB * NE) / 256), dim3(256), 0, stream>>>(inputs, emb, xbf);
    prep_v<<<dim3(1), dim3(512), 0, stream>>>(W_hq, b_q, dw, db, H0, v, c0, exch, cnt);

    void* args[] = { (void*)&C0, (void*)&b_i, (void*)&b_f, (void*)&b_o, (void*)&b_c,
                     (void*)&wpack, (void*)&xbf, (void*)&exch, (void*)&cnt, (void*)&v,
                     (void*)&ypart, (void*)&dout };
    hipLaunchCooperativeKernel((void*)lstm_coop, dim3(NWGT), dim3(256), args, 0, stream);

    reduce_y<<<dim3(65536 / 256), dim3(256), 0, stream>>>(ypart, c0, dout);
}

// Round 3
// 4237.135 us; speedup vs baseline: 2.0709x; 1.8148x over previous
//
#include <hip/hip_runtime.h>

// LSTM LM forward on gfx950.
// R13 = R10 protocol (proven 2941us), consolidated geometry: 8 WGs x 1024 thr
// per group (32 WGs total) instead of 32 x 256.
// R12 post-mortem: counter ready-signal TRAILED the data (vmcnt store-ack +
// hot-line fetch_add serialized in front of consumers) -> 7.9ms. Reverted to
// optimistic tag-polling. R11 post-mortem: phase-stagger algebra error.
// R13 theory: R10's wait (~5900cyc/step) is poll-BANDWIDTH contention:
// 32 WGs/group x 32KB = 4MB/round of agent-coherent (L2-bypassing) loads per
// resweep round machine-wide, ~1000cyc serialized fabric/LLC service per
// round. Consolidating to 8 WGs x 1024 thr cuts read duplication 4x
// (256KB/round/group) while keeping per-wave work, wfrag[20], and the
// exchange protocol bit-identical. Each thread sweeps hv[4] (was 16).
// Carried from R10: tagged u64 {step, 2xbf16} H exchange via relaxed
// AGENT-scope atomics, reload-all resweep with x-part MFMAs overlapping the
// poll, Hs parity dbuf + Xs triple-buf, one barrier/step, deferred Y flush
// via yred parity LDS + reduce_y, 2-way split accumulator, folded head
// Y = H.v + c0.

typedef short bf16x8 __attribute__((ext_vector_type(8)));
typedef float f32x4  __attribute__((ext_vector_type(4)));
typedef unsigned short ushort_t;
typedef unsigned long long u64;

#define S_LEN 1024
#define NB    64
#define NH    512
#define NE    128
#define NGRP  4
#define NWPG  8               // WGs per group (1024 threads each)
#define NWGT  32              // total WGs

// workspace byte offsets
#define OFF_WPACK 0UL                          // 128*20*64*16 = 2,621,440
#define OFF_XBF   2621440UL                    // 1024*64*128*2 = 16,777,216
#define OFF_EXCH  19398656UL                   // 4 grp * 2 par * 4096 u64 * 8 = 262,144
#define OFF_V     19660800UL                   // 512*4
#define OFF_C0S   19662848UL                   // 16
#define OFF_YPART 19663360UL                   // 1024*4*8*16*4 = 2,097,152

__device__ __forceinline__ ushort_t f2bf(float f){
    union { float f; unsigned u; } v; v.f = f;
    unsigned u = v.u;
    unsigned r = (u + 0x7fffu + ((u >> 16) & 1u)) >> 16;
    return (ushort_t)r;
}
__device__ __forceinline__ float sigm(float x){ return 1.f / (1.f + __expf(-x)); }
__device__ __forceinline__ float tanh_(float x){ float e = __expf(2.f * x); return (e - 1.f) / (e + 1.f); }

// ---- prep: pack W into MFMA A-operand fragments (bf16) ----------------------
// wpack[q][ks][lane][j]: A[m=lane&15][k=32*ks+(lane>>4)*8+j]; m -> h=4q+(m>>2),
// gate g=m&3; k<512: W_h[g][k][h]; k>=512: W_x[g][k-512][h]
__global__ void pack_weights(const float* __restrict__ Wxi, const float* __restrict__ Whi,
                             const float* __restrict__ Wxf, const float* __restrict__ Whf,
                             const float* __restrict__ Wxo, const float* __restrict__ Who,
                             const float* __restrict__ Wxc, const float* __restrict__ Whc,
                             ushort_t* __restrict__ wpack){
    int bid = blockIdx.x;            // = q*20 + ks
    int q = bid / 20, ks = bid % 20;
    int l = threadIdx.x;             // 0..63
    int m = l & 15, quad = l >> 4;
    int h = q * 4 + (m >> 2), g = m & 3;
    const float* Wh = (g == 0) ? Whi : (g == 1) ? Whf : (g == 2) ? Who : Whc;
    const float* Wx = (g == 0) ? Wxi : (g == 1) ? Wxf : (g == 2) ? Wxo : Wxc;
    union { ushort_t u[8]; uint4 v4; } tmp;
    #pragma unroll
    for (int j = 0; j < 8; j++){
        int k = ks * 32 + quad * 8 + j;
        float w = (k < NH) ? Wh[(size_t)k * NH + h] : Wx[(size_t)(k - NH) * NH + h];
        tmp.u[j] = f2bf(w);
    }
    *(uint4*)(wpack + ((size_t)bid * 64 + l) * 8) = tmp.v4;
}

// ---- prep: bf16 embeddings, layout [s][b][e] --------------------------------
__global__ void prep_x(const int* __restrict__ inputs, const float* __restrict__ emb,
                       ushort_t* __restrict__ xbf){
    unsigned tid = blockIdx.x * 256u + threadIdx.x;   // = (s*64+b)*128 + e
    unsigned e = tid & 127u;
    unsigned b = (tid >> 7) & 63u;
    unsigned s = tid >> 13;
    int row = inputs[(size_t)b * S_LEN + s];
    xbf[tid] = f2bf(emb[(size_t)row * NE + e]);
}

// ---- prep: v = W_hq @ dense_w, c0, exch init (H0, tag 0) --------------------
__global__ void prep_v(const float* __restrict__ Whq, const float* __restrict__ bq,
                       const float* __restrict__ dw, const float* __restrict__ db,
                       const float* __restrict__ H0, float* __restrict__ v,
                       float* __restrict__ c0, u64* __restrict__ exch){
    int t = threadIdx.x;   // 512 threads, 1 block
    float a = 0.f;
    for (int e = 0; e < NE; e++) a += Whq[(size_t)t * NE + e] * dw[e];
    v[t] = a;
    if (t == 0){
        float c = db[0];
        for (int e = 0; e < NE; e++) c += bq[e] * dw[e];
        *c0 = c;
    }
    // exch layout: [grp][parity][16 b_local][256 hpair] of u64 {tag, data}
    int p = t & 255, half = t >> 8;
    for (int b = half * 32; b < half * 32 + 32; b++){
        unsigned lo = (unsigned)f2bf(H0[(size_t)b * NH + 2 * p]) |
                      ((unsigned)f2bf(H0[(size_t)b * NH + 2 * p + 1]) << 16);
        exch[(size_t)(b >> 4) * 8192 + (size_t)(b & 15) * 256 + p] = (u64)lo;  // tag=0
    }
}

// ---- final: Y[s,b] = c0 + sum_wgin ypart[s][grp(b)][wgin][b&15] -------------
__global__ void reduce_y(const float* __restrict__ ypart, const float* __restrict__ c0,
                         float* __restrict__ dout){
    int t = blockIdx.x * 256 + threadIdx.x;   // t = s*64 + b, 65536 total
    int s = t >> 6, b = t & 63;
    int g = b >> 4, bl = b & 15;
    float a = *c0;
    const float* base = ypart + (((size_t)s * NGRP + g) * NWPG) * 16 + bl;
    #pragma unroll
    for (int w = 0; w < NWPG; w++) a += base[w * 16];
    dout[t] = a;
}

// ---- the recurrence ---------------------------------------------------------
__launch_bounds__(1024, 1)
__global__ void lstm_coop(const float* __restrict__ C0,
                          const float* __restrict__ b_i, const float* __restrict__ b_f,
                          const float* __restrict__ b_o, const float* __restrict__ b_c,
                          const ushort_t* __restrict__ wpack, const ushort_t* __restrict__ xbf,
                          u64* __restrict__ exch, const float* __restrict__ v,
                          float* __restrict__ ypart, float* __restrict__ dout){
    // LDS: Hs double-buffered [2][16 rows][65 uint4] (+pad -> dword stride 260,
    // conflict-free staging), Xs triple-buffered [3][16][17] uint4,
    // yred parity-double-buffered wave partials (16 waves now).
    __shared__ uint4 Hs[2][16][65];
    __shared__ uint4 Xs[3][16][17];
    __shared__ float yred[2][16][16];

    const int tid  = threadIdx.x;          // 0..1023
    const int lane = tid & 63;
    const int wv   = tid >> 6;             // 0..15
    const int wg   = blockIdx.x;           // 0..31
    const int g    = wg >> 3;              // batch group 0..3
    const int wgin = wg & 7;               // WG index within group 0..7
    const int q    = wgin * 16 + wv;       // h-slot 0..127
    const int quad = lane >> 4;
    const int col  = lane & 15;
    const int h    = q * 4 + quad;         // this lane's h column
    const int b    = g * 16 + col;         // this lane's batch

    // persistent weights: 20 A-fragments (K=640)
    bf16x8 wfrag[20];
    #pragma unroll
    for (int ks = 0; ks < 20; ks++)
        wfrag[ks] = *(const bf16x8*)(wpack + ((size_t)(q * 20 + ks) * 64 + lane) * 8);

    const float bias0 = b_i[h], bias1 = b_f[h], bias2 = b_o[h], bias3 = b_c[h];
    const float vv = v[h];
    float C = C0[(size_t)b * NH + h];

    u64* exg = exch + (size_t)g * 8192;    // this group's double buffer

    const char* HsB = (const char*)Hs;
    const char* XsB = (const char*)Xs;
    unsigned* HsD = (unsigned*)Hs;

    // preload x tile for s=0 into Xs[0]; barrier so early x-MFMAs at s=0 are safe
    if (tid < 256){
        const uint4* x0 = (const uint4*)(xbf + (size_t)(g * 16) * NE);
        Xs[0][tid >> 4][tid & 15] = x0[tid];
    }
    __syncthreads();

    for (int s = 0; s < S_LEN; s++){
        // x prefetch for s+1 (lands during poll); only waves 0-3 participate
        uint4 xr = {0, 0, 0, 0};
        if (tid < 256){
            int sn = (s + 1 < S_LEN) ? s + 1 : s;
            xr = ((const uint4*)(xbf + ((size_t)sn * NB + g * 16) * NE))[tid];
        }

        // ---- issue poll loads for H(s): 4 words/thread (1024 thr cover 4096) -
        const u64* ex = exg + (size_t)(s & 1) * 4096;
        const unsigned tag = (unsigned)s;
        u64 hv[4];
        #pragma unroll
        for (int j = 0; j < 4; j++)
            hv[j] = __hip_atomic_load(ex + (size_t)j * 1024 + tid, __ATOMIC_RELAXED,
                                      __HIP_MEMORY_SCOPE_AGENT);

        // ---- x-part MFMAs overlap the poll (Xs[s%3] synced at step s-1) ------
        f32x4 acc0 = (f32x4){0.f, 0.f, 0.f, 0.f};
        f32x4 acc1 = (f32x4){0.f, 0.f, 0.f, 0.f};
        #pragma unroll
        for (int kx = 0; kx < 4; kx++){
            bf16x8 bfr = *(const bf16x8*)(XsB + (s % 3) * 4352 + col * 272 + kx * 64 + quad * 16);
            if (kx & 1) acc1 = __builtin_amdgcn_mfma_f32_16x16x32_bf16(wfrag[16 + kx], bfr, acc1, 0, 0, 0);
            else        acc0 = __builtin_amdgcn_mfma_f32_16x16x32_bf16(wfrag[16 + kx], bfr, acc0, 0, 0, 0);
        }

        // ---- finish poll: reload-all resweep until every tag matches ---------
        for (;;){
            unsigned bad = 0;
            #pragma unroll
            for (int j = 0; j < 4; j++)
                bad |= ((unsigned)(hv[j] >> 32) != tag) ? 1u : 0u;
            if (!bad) break;
            __builtin_amdgcn_s_sleep(1);
            #pragma unroll
            for (int j = 0; j < 4; j++)
                hv[j] = __hip_atomic_load(ex + (size_t)j * 1024 + tid, __ATOMIC_RELAXED,
                                          __HIP_MEMORY_SCOPE_AGENT);
        }
        // word w = j*1024+tid -> b_local = w>>8, pair = w&255
        #pragma unroll
        for (int j = 0; j < 4; j++)
            HsD[(s & 1) * 4160 + (j * 4 + (tid >> 8)) * 260 + (tid & 255)] = (unsigned)hv[j];
        if (tid < 256) Xs[(s + 1) % 3][tid >> 4][tid & 15] = xr;
        __syncthreads();   // the only in-loop barrier: Hs[s&1] + Xs ready

        // ---- flush previous step's Y partials (reuses this barrier) ----------
        if (tid < 16 && s > 0){
            float yy = 0.f;
            #pragma unroll
            for (int w = 0; w < 16; w++) yy += yred[(s - 1) & 1][w][tid];
            ypart[(((size_t)(s - 1) * NGRP + g) * NWPG + wgin) * 16 + tid] = yy;
        }

        // ---- H-part: 16 MFMA from LDS (2-way split accumulator) --------------
        #pragma unroll
        for (int ks = 0; ks < 16; ks++){
            bf16x8 bfr = *(const bf16x8*)(HsB + (s & 1) * 16640 + col * 1040 + ks * 64 + quad * 16);
            if (ks & 1) acc1 = __builtin_amdgcn_mfma_f32_16x16x32_bf16(wfrag[ks], bfr, acc1, 0, 0, 0);
            else        acc0 = __builtin_amdgcn_mfma_f32_16x16x32_bf16(wfrag[ks], bfr, acc0, 0, 0, 0);
        }
        f32x4 acc = acc0 + acc1;

        // ---- cell update: acc regs = {i,f,o,c} for (b, h) ---------------------
        float I = sigm(acc[0] + bias0);
        float F = sigm(acc[1] + bias1);
        float O = sigm(acc[2] + bias2);
        float G = tanh_(acc[3] + bias3);
        float Cn = F * C + I * G;
        float Hn = O * tanh_(Cn);
        C = Cn;

        // ---- publish H(s+1): tagged u64, lane-pair packed, fire-and-forget ----
        float Hn_hi = __shfl_xor(Hn, 16, 64);         // partner quad's value
        {
            unsigned lo = (unsigned)f2bf(Hn) | ((unsigned)f2bf(Hn_hi) << 16);
            if ((quad & 1) == 0 && s < S_LEN - 1){
                u64* ew = exg + (size_t)((s + 1) & 1) * 4096;
                unsigned idx = (unsigned)col * 256 + (unsigned)(q * 2) + (unsigned)(quad >> 1);
                u64 word = ((u64)(unsigned)(s + 1) << 32) | (u64)lo;
                __hip_atomic_store(ew + idx, word, __ATOMIC_RELAXED,
                                   __HIP_MEMORY_SCOPE_AGENT);
            }
        }

        // ---- Y partial into LDS (read after NEXT step's barrier) -------------
        float p = Hn * vv;
        p += __shfl_xor(p, 16, 64);
        p += __shfl_xor(p, 32, 64);
        if (quad == 0) yred[s & 1][wv][col] = p;

        if (s == S_LEN - 1){
            dout[65536 + (size_t)b * NH + h] = Hn;   // final H
            dout[98304 + (size_t)b * NH + h] = Cn;   // final C
        }
    }
    // final Y flush for s = S_LEN-1
    __syncthreads();
    if (tid < 16){
        float yy = 0.f;
        #pragma unroll
        for (int w = 0; w < 16; w++) yy += yred[(S_LEN - 1) & 1][w][tid];
        ypart[(((size_t)(S_LEN - 1) * NGRP + g) * NWPG + wgin) * 16 + tid] = yy;
    }
}

extern "C" void kernel_launch(void* const* d_in, const int* in_sizes, int n_in,
                              void* d_out, int out_size, void* d_ws, size_t ws_size,
                              hipStream_t stream){
    const int*   inputs = (const int*)  d_in[0];
    const float* H0     = (const float*)d_in[1];
    const float* C0     = (const float*)d_in[2];
    const float* emb    = (const float*)d_in[3];
    const float* W_xi   = (const float*)d_in[4];
    const float* W_hi   = (const float*)d_in[5];
    const float* b_i    = (const float*)d_in[6];
    const float* W_xf   = (const float*)d_in[7];
    const float* W_hf   = (const float*)d_in[8];
    const float* b_f    = (const float*)d_in[9];
    const float* W_xo   = (const float*)d_in[10];
    const float* W_ho   = (const float*)d_in[11];
    const float* b_o    = (const float*)d_in[12];
    const float* W_xc   = (const float*)d_in[13];
    const float* W_hc   = (const float*)d_in[14];
    const float* b_c    = (const float*)d_in[15];
    const float* W_hq   = (const float*)d_in[16];
    const float* b_q    = (const float*)d_in[17];
    const float* dw     = (const float*)d_in[18];
    const float* db     = (const float*)d_in[19];
    float* dout = (float*)d_out;

    char* ws = (char*)d_ws;
    ushort_t* wpack = (ushort_t*)(ws + OFF_WPACK);
    ushort_t* xbf   = (ushort_t*)(ws + OFF_XBF);
    u64*      exch  = (u64*)     (ws + OFF_EXCH);
    float*    v     = (float*)   (ws + OFF_V);
    float*    c0    = (float*)   (ws + OFF_C0S);
    float*    ypart = (float*)   (ws + OFF_YPART);

    pack_weights<<<dim3(128 * 20), dim3(64), 0, stream>>>(W_xi, W_hi, W_xf, W_hf,
                                                          W_xo, W_ho, W_xc, W_hc, wpack);
    prep_x<<<dim3((S_LEN * NB * NE) / 256), dim3(256), 0, stream>>>(inputs, emb, xbf);
    prep_v<<<dim3(1), dim3(512), 0, stream>>>(W_hq, b_q, dw, db, H0, v, c0, exch);

    void* args[] = { (void*)&C0, (void*)&b_i, (void*)&b_f, (void*)&b_o, (void*)&b_c,
                     (void*)&wpack, (void*)&xbf, (void*)&exch, (void*)&v,
                     (void*)&ypart, (void*)&dout };
    hipLaunchCooperativeKernel((void*)lstm_coop, dim3(NWGT), dim3(1024), args, 0, stream);

    reduce_y<<<dim3(65536 / 256), dim3(256), 0, stream>>>(ypart, c0, dout);
}